// Round 10
// baseline (987.677 us; speedup 1.0000x reference)
//
#include <hip/hip_runtime.h>

#define NT 512   // T
#define NB 128   // B
#define ND 256   // D
#define NH 256   // H

typedef _Float16 half4v __attribute__((ext_vector_type(4)));
typedef float f32x4 __attribute__((ext_vector_type(4)));
typedef float f4 __attribute__((ext_vector_type(4)));
typedef unsigned int u4 __attribute__((ext_vector_type(4)));

#define MFMA16(a, b, c) \
    __builtin_amdgcn_mfma_f32_16x16x16f16((a), (b), (c), 0, 0, 0)

// ---------------------------------------------------------------------------
// Phase 1: Z = X @ Wi^T + bh.  Register-tiled fp32 GEMM (unchanged, proven).
// ---------------------------------------------------------------------------
__global__ __launch_bounds__(256) void zprep_kernel(
    const float* __restrict__ X, const float* __restrict__ Wi,
    const float* __restrict__ bh, float* __restrict__ Z)
{
    __shared__ float xsT[64][68];   // [k][m]
    __shared__ float wsT[64][68];   // [k][j]
    const int tid = threadIdx.x;
    const int tm  = tid & 15, tj = tid >> 4;
    const int m0  = blockIdx.x * 64;
    const int j0  = blockIdx.y * 64;
    const int sm  = tid >> 2, kq = tid & 3;

    float acc[4][4] = {};

    for (int c = 0; c < 4; ++c) {
        const int k0 = c * 64;
        const float* xr = X  + (size_t)(m0 + sm) * ND + k0 + kq * 16;
        const float* wr = Wi + (size_t)(j0 + sm) * ND + k0 + kq * 16;
        #pragma unroll
        for (int i = 0; i < 4; ++i) {
            const float4 xv = *(const float4*)(xr + i * 4);
            const float4 wv = *(const float4*)(wr + i * 4);
            const int kk = kq * 16 + i * 4;
            xsT[kk + 0][sm] = xv.x; xsT[kk + 1][sm] = xv.y;
            xsT[kk + 2][sm] = xv.z; xsT[kk + 3][sm] = xv.w;
            wsT[kk + 0][sm] = wv.x; wsT[kk + 1][sm] = wv.y;
            wsT[kk + 2][sm] = wv.z; wsT[kk + 3][sm] = wv.w;
        }
        __syncthreads();

        #pragma unroll 8
        for (int k = 0; k < 64; ++k) {
            const float4 x4 = *(const float4*)&xsT[k][tm * 4];
            const float4 w4 = *(const float4*)&wsT[k][tj * 4];
            acc[0][0] = fmaf(x4.x, w4.x, acc[0][0]);
            acc[0][1] = fmaf(x4.x, w4.y, acc[0][1]);
            acc[0][2] = fmaf(x4.x, w4.z, acc[0][2]);
            acc[0][3] = fmaf(x4.x, w4.w, acc[0][3]);
            acc[1][0] = fmaf(x4.y, w4.x, acc[1][0]);
            acc[1][1] = fmaf(x4.y, w4.y, acc[1][1]);
            acc[1][2] = fmaf(x4.y, w4.z, acc[1][2]);
            acc[1][3] = fmaf(x4.y, w4.w, acc[1][3]);
            acc[2][0] = fmaf(x4.z, w4.x, acc[2][0]);
            acc[2][1] = fmaf(x4.z, w4.y, acc[2][1]);
            acc[2][2] = fmaf(x4.z, w4.z, acc[2][2]);
            acc[2][3] = fmaf(x4.z, w4.w, acc[2][3]);
            acc[3][0] = fmaf(x4.w, w4.x, acc[3][0]);
            acc[3][1] = fmaf(x4.w, w4.y, acc[3][1]);
            acc[3][2] = fmaf(x4.w, w4.z, acc[3][2]);
            acc[3][3] = fmaf(x4.w, w4.w, acc[3][3]);
        }
        __syncthreads();
    }

    const float4 b4 = *(const float4*)&bh[j0 + tj * 4];
    #pragma unroll
    for (int r = 0; r < 4; ++r) {
        float4 o;
        o.x = acc[r][0] + b4.x; o.y = acc[r][1] + b4.y;
        o.z = acc[r][2] + b4.z; o.w = acc[r][3] + b4.w;
        *(float4*)&Z[(size_t)(m0 + tm * 4 + r) * NH + j0 + tj * 4] = o;
    }
}

// ---------------------------------------------------------------------------
// Phase 2: MFMA recurrence with PERSISTENT register-resident weights.
// 8 WGs x 16 batch rows; 256 threads = 4 waves; wave w owns cols [64w,64w+64).
// Weights: 64 B-fragments/wave (f16, v_mfma_f32_16x16x16_f16) = 128 VGPRs,
// loaded ONCE via batched asm-volatile global_load_dwordx4 (unsinkable).
// R9 CRASH FIX: outputs are now EARLY-CLOBBER ("=&v") — with plain "=v" the
// allocator could overlap an output quad with the base-address pair, and an
// early out-of-order data return clobbered the address for later loads.
// launch_bounds(256,1) -> VGPR cap 512 >> demand ~220 -> no spill pressure.
// Layouts (16x16x16): A lane l: m=l%16, k=(l/16)*4+i. B lane l: n=l%16,
// same k (B[k][n]=Wh[n][k] -> lane reads Wh row n contiguous in k).
// D lane l reg r: n=l%16, m=(l/16)*4+r (m89-verified family).
// Per step: 16 ds_read_b64 A-frags from double-buffered h LDS (pitch 264
// halves), 64 MFMAs with C init from prefetched Z_t, sigmoid, f32 store +
// f16 LDS write, ONE barrier.
// ---------------------------------------------------------------------------
#define HP 264   // h LDS pitch in halves (528 B rows)

#define CVT4(dst, q) do {                         \
    const f4 f_ = __builtin_bit_cast(f4, (q));    \
    (dst)[0] = (_Float16)f_[0];                   \
    (dst)[1] = (_Float16)f_[1];                   \
    (dst)[2] = (_Float16)f_[2];                   \
    (dst)[3] = (_Float16)f_[3];                   \
} while (0)

#define PIN4(x) do {                                   \
    double d_ = __builtin_bit_cast(double, (x));       \
    asm volatile("" : "+v"(d_));                       \
    (x) = __builtin_bit_cast(half4v, d_);              \
} while (0)

// one batched unsinkable load of 16 x 16B from base+{0,64,...,960}
// ALL outputs early-clobber so none can alias the address pair.
#define LOAD_BASE(wfA, base) do {                                         \
    u4 q0,q1,q2,q3,q4,q5,q6,q7,q8,q9,q10,q11,q12,q13,q14,q15;             \
    asm volatile(                                                         \
        "global_load_dwordx4 %0, %16, off offset:0\n\t"                   \
        "global_load_dwordx4 %1, %16, off offset:64\n\t"                  \
        "global_load_dwordx4 %2, %16, off offset:128\n\t"                 \
        "global_load_dwordx4 %3, %16, off offset:192\n\t"                 \
        "global_load_dwordx4 %4, %16, off offset:256\n\t"                 \
        "global_load_dwordx4 %5, %16, off offset:320\n\t"                 \
        "global_load_dwordx4 %6, %16, off offset:384\n\t"                 \
        "global_load_dwordx4 %7, %16, off offset:448\n\t"                 \
        "global_load_dwordx4 %8, %16, off offset:512\n\t"                 \
        "global_load_dwordx4 %9, %16, off offset:576\n\t"                 \
        "global_load_dwordx4 %10, %16, off offset:640\n\t"                \
        "global_load_dwordx4 %11, %16, off offset:704\n\t"                \
        "global_load_dwordx4 %12, %16, off offset:768\n\t"                \
        "global_load_dwordx4 %13, %16, off offset:832\n\t"                \
        "global_load_dwordx4 %14, %16, off offset:896\n\t"                \
        "global_load_dwordx4 %15, %16, off offset:960\n\t"                \
        "s_waitcnt vmcnt(0)"                                              \
        : "=&v"(q0),"=&v"(q1),"=&v"(q2),"=&v"(q3),"=&v"(q4),"=&v"(q5),    \
          "=&v"(q6),"=&v"(q7),"=&v"(q8),"=&v"(q9),"=&v"(q10),"=&v"(q11),  \
          "=&v"(q12),"=&v"(q13),"=&v"(q14),"=&v"(q15)                     \
        : "v"(base));                                                     \
    CVT4(wfA[0], q0);   CVT4(wfA[1], q1);   CVT4(wfA[2], q2);             \
    CVT4(wfA[3], q3);   CVT4(wfA[4], q4);   CVT4(wfA[5], q5);             \
    CVT4(wfA[6], q6);   CVT4(wfA[7], q7);   CVT4(wfA[8], q8);             \
    CVT4(wfA[9], q9);   CVT4(wfA[10], q10); CVT4(wfA[11], q11);           \
    CVT4(wfA[12], q12); CVT4(wfA[13], q13); CVT4(wfA[14], q14);           \
    CVT4(wfA[15], q15);                                                   \
} while (0)

__global__ __launch_bounds__(256, 1) void rnn_step_kernel(
    float* __restrict__ ZO,
    const float* __restrict__ h0,
    const float* __restrict__ Wh)
{
    __shared__ _Float16 hl[2][16 * HP];
    const int tid = threadIdx.x;
    const int b0  = blockIdx.x * 16;
    const int w4  = (tid >> 6) * 4;   // wave's first n-tile
    const int l   = tid & 63;
    const int ln  = l & 15;
    const int lg  = l >> 4;

    // ---- persistent weight fragments (one-time) ----
    half4v wf0[16], wf1[16], wf2[16], wf3[16];
    {
        const size_t lgo = (size_t)lg * 4;
        const unsigned long long bA =
            (unsigned long long)(Wh + (size_t)((w4 + 0) * 16 + ln) * NH + lgo);
        const unsigned long long bB =
            (unsigned long long)(Wh + (size_t)((w4 + 1) * 16 + ln) * NH + lgo);
        const unsigned long long bC =
            (unsigned long long)(Wh + (size_t)((w4 + 2) * 16 + ln) * NH + lgo);
        const unsigned long long bD =
            (unsigned long long)(Wh + (size_t)((w4 + 3) * 16 + ln) * NH + lgo);
        LOAD_BASE(wf0, bA);
        LOAD_BASE(wf1, bB);
        LOAD_BASE(wf2, bC);
        LOAD_BASE(wf3, bD);
    }
    #pragma unroll
    for (int i = 0; i < 16; ++i) {
        PIN4(wf0[i]); PIN4(wf1[i]); PIN4(wf2[i]); PIN4(wf3[i]);
    }

    // ---- stage h0 into LDS buffer 0 ----
    {
        const int m  = tid >> 4;
        const int c0 = (tid & 15) * 16;
        const float* hp = h0 + (size_t)(b0 + m) * NH + c0;
        #pragma unroll
        for (int j = 0; j < 16; ++j)
            hl[0][m * HP + c0 + j] = (_Float16)hp[j];
    }

    // ---- prefetch Z for t = 0 ----
    f32x4 zf0, zf1, zf2, zf3;
    {
        const float* zp = ZO + ((size_t)0 * NB + b0 + lg * 4) * NH;
        const int n0 = (w4 + 0) * 16 + ln, n1 = (w4 + 1) * 16 + ln;
        const int n2 = (w4 + 2) * 16 + ln, n3 = (w4 + 3) * 16 + ln;
        zf0[0]=zp[n0]; zf0[1]=zp[NH+n0]; zf0[2]=zp[2*NH+n0]; zf0[3]=zp[3*NH+n0];
        zf1[0]=zp[n1]; zf1[1]=zp[NH+n1]; zf1[2]=zp[2*NH+n1]; zf1[3]=zp[3*NH+n1];
        zf2[0]=zp[n2]; zf2[1]=zp[NH+n2]; zf2[2]=zp[2*NH+n2]; zf2[3]=zp[3*NH+n2];
        zf3[0]=zp[n3]; zf3[1]=zp[NH+n3]; zf3[2]=zp[2*NH+n3]; zf3[3]=zp[3*NH+n3];
    }
    __syncthreads();

    int cur = 0;
    for (int t = 0; t < NT; ++t) {
        // A-fragments: h[m=ln][k = kt*16 + lg*4 .. +4), 16 x ds_read_b64
        half4v af[16];
        #pragma unroll
        for (int kt = 0; kt < 16; ++kt)
            af[kt] = *(const half4v*)&hl[cur][ln * HP + kt * 16 + lg * 4];

        // acc = Z_t (C-operand init), then prefetch Z_{t+1}
        f32x4 acc0 = zf0, acc1 = zf1, acc2 = zf2, acc3 = zf3;
        {
            const int tn = (t + 1 < NT) ? t + 1 : t;
            const float* zp = ZO + ((size_t)tn * NB + b0 + lg * 4) * NH;
            const int n0 = (w4 + 0) * 16 + ln, n1 = (w4 + 1) * 16 + ln;
            const int n2 = (w4 + 2) * 16 + ln, n3 = (w4 + 3) * 16 + ln;
            zf0[0]=zp[n0]; zf0[1]=zp[NH+n0]; zf0[2]=zp[2*NH+n0]; zf0[3]=zp[3*NH+n0];
            zf1[0]=zp[n1]; zf1[1]=zp[NH+n1]; zf1[2]=zp[2*NH+n1]; zf1[3]=zp[3*NH+n1];
            zf2[0]=zp[n2]; zf2[1]=zp[NH+n2]; zf2[2]=zp[2*NH+n2]; zf2[3]=zp[3*NH+n2];
            zf3[0]=zp[n3]; zf3[1]=zp[NH+n3]; zf3[2]=zp[2*NH+n3]; zf3[3]=zp[3*NH+n3];
        }

        #pragma unroll
        for (int kt = 0; kt < 16; ++kt) {
            acc0 = MFMA16(af[kt], wf0[kt], acc0);
            acc1 = MFMA16(af[kt], wf1[kt], acc1);
            acc2 = MFMA16(af[kt], wf2[kt], acc2);
            acc3 = MFMA16(af[kt], wf3[kt], acc3);
        }

        // sigmoid -> global f32 store + LDS f16 write (next buffer)
        {
            float* op = ZO + ((size_t)t * NB + b0 + lg * 4) * NH;
            _Float16* lp = &hl[cur ^ 1][(lg * 4) * HP];
            #define FIN(accX, NT2) do {                                     \
                const int n_ = (w4 + NT2) * 16 + ln;                        \
                const float v0_ = 1.0f / (1.0f + __expf(-(accX)[0]));       \
                const float v1_ = 1.0f / (1.0f + __expf(-(accX)[1]));       \
                const float v2_ = 1.0f / (1.0f + __expf(-(accX)[2]));       \
                const float v3_ = 1.0f / (1.0f + __expf(-(accX)[3]));       \
                op[n_] = v0_;          op[NH + n_] = v1_;                   \
                op[2 * NH + n_] = v2_; op[3 * NH + n_] = v3_;               \
                lp[n_] = (_Float16)v0_;          lp[HP + n_] = (_Float16)v1_; \
                lp[2 * HP + n_] = (_Float16)v2_; lp[3 * HP + n_] = (_Float16)v3_; \
            } while (0)
            FIN(acc0, 0); FIN(acc1, 1); FIN(acc2, 2); FIN(acc3, 3);
            #undef FIN
        }
        __syncthreads();
        cur ^= 1;
    }
}

extern "C" void kernel_launch(void* const* d_in, const int* in_sizes, int n_in,
                              void* d_out, int out_size, void* d_ws, size_t ws_size,
                              hipStream_t stream) {
    const float* X  = (const float*)d_in[0];
    const float* h0 = (const float*)d_in[1];
    const float* Wi = (const float*)d_in[2];
    const float* Wh = (const float*)d_in[3];
    const float* bh = (const float*)d_in[4];
    float* out = (float*)d_out;

    dim3 zgrid((NT * NB) / 64, NH / 64);
    zprep_kernel<<<zgrid, 256, 0, stream>>>(X, Wi, bh, out);
    rnn_step_kernel<<<NB / 16, 256, 0, stream>>>(out, h0, Wh);
}

// Round 11
// 687.939 us; speedup vs baseline: 1.4357x; 1.4357x over previous
//
#include <hip/hip_runtime.h>

#define NT 512   // T
#define NB 128   // B
#define ND 256   // D
#define NH 256   // H

typedef _Float16 half4v __attribute__((ext_vector_type(4)));
typedef float f32x4 __attribute__((ext_vector_type(4)));
typedef float f4 __attribute__((ext_vector_type(4)));
typedef unsigned int u4 __attribute__((ext_vector_type(4)));

#define MFMA16(a, b, c) \
    __builtin_amdgcn_mfma_f32_16x16x16f16((a), (b), (c), 0, 0, 0)

// ---------------------------------------------------------------------------
// Phase 1: Z = X @ Wi^T + bh.  Register-tiled fp32 GEMM (unchanged, proven).
// ---------------------------------------------------------------------------
__global__ __launch_bounds__(256) void zprep_kernel(
    const float* __restrict__ X, const float* __restrict__ Wi,
    const float* __restrict__ bh, float* __restrict__ Z)
{
    __shared__ float xsT[64][68];   // [k][m]
    __shared__ float wsT[64][68];   // [k][j]
    const int tid = threadIdx.x;
    const int tm  = tid & 15, tj = tid >> 4;
    const int m0  = blockIdx.x * 64;
    const int j0  = blockIdx.y * 64;
    const int sm  = tid >> 2, kq = tid & 3;

    float acc[4][4] = {};

    for (int c = 0; c < 4; ++c) {
        const int k0 = c * 64;
        const float* xr = X  + (size_t)(m0 + sm) * ND + k0 + kq * 16;
        const float* wr = Wi + (size_t)(j0 + sm) * ND + k0 + kq * 16;
        #pragma unroll
        for (int i = 0; i < 4; ++i) {
            const float4 xv = *(const float4*)(xr + i * 4);
            const float4 wv = *(const float4*)(wr + i * 4);
            const int kk = kq * 16 + i * 4;
            xsT[kk + 0][sm] = xv.x; xsT[kk + 1][sm] = xv.y;
            xsT[kk + 2][sm] = xv.z; xsT[kk + 3][sm] = xv.w;
            wsT[kk + 0][sm] = wv.x; wsT[kk + 1][sm] = wv.y;
            wsT[kk + 2][sm] = wv.z; wsT[kk + 3][sm] = wv.w;
        }
        __syncthreads();

        #pragma unroll 8
        for (int k = 0; k < 64; ++k) {
            const float4 x4 = *(const float4*)&xsT[k][tm * 4];
            const float4 w4 = *(const float4*)&wsT[k][tj * 4];
            acc[0][0] = fmaf(x4.x, w4.x, acc[0][0]);
            acc[0][1] = fmaf(x4.x, w4.y, acc[0][1]);
            acc[0][2] = fmaf(x4.x, w4.z, acc[0][2]);
            acc[0][3] = fmaf(x4.x, w4.w, acc[0][3]);
            acc[1][0] = fmaf(x4.y, w4.x, acc[1][0]);
            acc[1][1] = fmaf(x4.y, w4.y, acc[1][1]);
            acc[1][2] = fmaf(x4.y, w4.z, acc[1][2]);
            acc[1][3] = fmaf(x4.y, w4.w, acc[1][3]);
            acc[2][0] = fmaf(x4.z, w4.x, acc[2][0]);
            acc[2][1] = fmaf(x4.z, w4.y, acc[2][1]);
            acc[2][2] = fmaf(x4.z, w4.z, acc[2][2]);
            acc[2][3] = fmaf(x4.z, w4.w, acc[2][3]);
            acc[3][0] = fmaf(x4.w, w4.x, acc[3][0]);
            acc[3][1] = fmaf(x4.w, w4.y, acc[3][1]);
            acc[3][2] = fmaf(x4.w, w4.z, acc[3][2]);
            acc[3][3] = fmaf(x4.w, w4.w, acc[3][3]);
        }
        __syncthreads();
    }

    const float4 b4 = *(const float4*)&bh[j0 + tj * 4];
    #pragma unroll
    for (int r = 0; r < 4; ++r) {
        float4 o;
        o.x = acc[r][0] + b4.x; o.y = acc[r][1] + b4.y;
        o.z = acc[r][2] + b4.z; o.w = acc[r][3] + b4.w;
        *(float4*)&Z[(size_t)(m0 + tm * 4 + r) * NH + j0 + tj * 4] = o;
    }
}

// ---------------------------------------------------------------------------
// Phase 2: MFMA recurrence, persistent weights (R10 skeleton — layouts
// verified correct — with the three performance fixes):
//  * 512 threads = 8 waves (2/SIMD, TLP): wave w owns cols [32w, 32w+32)
//    = n-tiles {2w, 2w+1}; 32 MFMAs/step/wave, 32 weight frags = 64 VGPRs.
//  * Loop barrier = s_waitcnt lgkmcnt(0); s_barrier ONLY. __syncthreads'
//    vmcnt(0) drain put the Z-prefetch + store latency (~1000 cyc) on the
//    critical path every step (R10's 4120 cyc/step). Z reads (row t+1) and
//    h stores (row t) are disjoint addresses; h exchange is LDS-only, so
//    only lgkmcnt must drain. Globals stay in flight across the barrier.
//  * LDS pitch 260 halves (520 B): P/4 = 130 = 2 mod 32 -> start bank
//    2*(ln+lg) uniform over even banks -> minimal 4-sweep for wave64 b64;
//    FIN writes land 2 lanes/bank (free).  (R10: HP=264 -> 1M conflicts.)
// Layouts (16x16x16 f16): A lane l: m=l%16, k=(l/16)*4+i (h from LDS).
// B lane l: n=l%16, k=(l/16)*4+i = Wh[n][k], row-contiguous. D lane l reg
// r: m=(l/16)*4+r, n=l%16. acc C-initialized with Z_t (prefetched).
// ---------------------------------------------------------------------------
#define P 260   // h LDS pitch in halves (520 B rows)

#define CVT4(dst, q) do {                         \
    const f4 f_ = __builtin_bit_cast(f4, (q));    \
    (dst)[0] = (_Float16)f_[0];                   \
    (dst)[1] = (_Float16)f_[1];                   \
    (dst)[2] = (_Float16)f_[2];                   \
    (dst)[3] = (_Float16)f_[3];                   \
} while (0)

#define PIN4(x) do {                                   \
    double d_ = __builtin_bit_cast(double, (x));       \
    asm volatile("" : "+v"(d_));                       \
    (x) = __builtin_bit_cast(half4v, d_);              \
} while (0)

// batched unsinkable load of 16 x 16B from base+{0,64,...,960}; outputs
// early-clobber so none alias the address pair (R9 crash fix, R10-proven).
#define LOAD_BASE(wfA, base) do {                                         \
    u4 q0,q1,q2,q3,q4,q5,q6,q7,q8,q9,q10,q11,q12,q13,q14,q15;             \
    asm volatile(                                                         \
        "global_load_dwordx4 %0, %16, off offset:0\n\t"                   \
        "global_load_dwordx4 %1, %16, off offset:64\n\t"                  \
        "global_load_dwordx4 %2, %16, off offset:128\n\t"                 \
        "global_load_dwordx4 %3, %16, off offset:192\n\t"                 \
        "global_load_dwordx4 %4, %16, off offset:256\n\t"                 \
        "global_load_dwordx4 %5, %16, off offset:320\n\t"                 \
        "global_load_dwordx4 %6, %16, off offset:384\n\t"                 \
        "global_load_dwordx4 %7, %16, off offset:448\n\t"                 \
        "global_load_dwordx4 %8, %16, off offset:512\n\t"                 \
        "global_load_dwordx4 %9, %16, off offset:576\n\t"                 \
        "global_load_dwordx4 %10, %16, off offset:640\n\t"                \
        "global_load_dwordx4 %11, %16, off offset:704\n\t"                \
        "global_load_dwordx4 %12, %16, off offset:768\n\t"                \
        "global_load_dwordx4 %13, %16, off offset:832\n\t"                \
        "global_load_dwordx4 %14, %16, off offset:896\n\t"                \
        "global_load_dwordx4 %15, %16, off offset:960\n\t"                \
        "s_waitcnt vmcnt(0)"                                              \
        : "=&v"(q0),"=&v"(q1),"=&v"(q2),"=&v"(q3),"=&v"(q4),"=&v"(q5),    \
          "=&v"(q6),"=&v"(q7),"=&v"(q8),"=&v"(q9),"=&v"(q10),"=&v"(q11),  \
          "=&v"(q12),"=&v"(q13),"=&v"(q14),"=&v"(q15)                     \
        : "v"(base));                                                     \
    CVT4(wfA[0], q0);   CVT4(wfA[1], q1);   CVT4(wfA[2], q2);             \
    CVT4(wfA[3], q3);   CVT4(wfA[4], q4);   CVT4(wfA[5], q5);             \
    CVT4(wfA[6], q6);   CVT4(wfA[7], q7);   CVT4(wfA[8], q8);             \
    CVT4(wfA[9], q9);   CVT4(wfA[10], q10); CVT4(wfA[11], q11);           \
    CVT4(wfA[12], q12); CVT4(wfA[13], q13); CVT4(wfA[14], q14);           \
    CVT4(wfA[15], q15);                                                   \
} while (0)

// LDS-only barrier: h exchange needs lgkmcnt drain, NOT vmcnt.
#define BAR() asm volatile("s_waitcnt lgkmcnt(0)\n\ts_barrier" ::: "memory")

__global__ __launch_bounds__(512, 1) void rnn_step_kernel(
    float* __restrict__ ZO,
    const float* __restrict__ h0,
    const float* __restrict__ Wh)
{
    __shared__ _Float16 hl[2][16 * P];
    const int tid = threadIdx.x;
    const int b0  = blockIdx.x * 16;
    const int w   = tid >> 6;        // wave 0..7
    const int l   = tid & 63;
    const int ln  = l & 15;
    const int lg  = l >> 4;
    const int n0  = w * 32 + ln;       // col in n-tile 2w
    const int n1  = w * 32 + 16 + ln;  // col in n-tile 2w+1

    // ---- persistent weight fragments (one-time, unsinkable) ----
    half4v wf0[16], wf1[16];
    {
        const size_t lgo = (size_t)lg * 4;
        const unsigned long long bA =
            (unsigned long long)(Wh + (size_t)n0 * NH + lgo);
        const unsigned long long bB =
            (unsigned long long)(Wh + (size_t)n1 * NH + lgo);
        LOAD_BASE(wf0, bA);
        LOAD_BASE(wf1, bB);
    }
    #pragma unroll
    for (int i = 0; i < 16; ++i) { PIN4(wf0[i]); PIN4(wf1[i]); }

    // ---- stage h0 into LDS buffer 0 (16 rows x 256 cols, f32 -> f16) ----
    {
        const int m  = tid >> 5;
        const int c0 = (tid & 31) * 8;
        const float* hp = h0 + (size_t)(b0 + m) * NH + c0;
        const float4 a = *(const float4*)(hp);
        const float4 c = *(const float4*)(hp + 4);
        _Float16* d = &hl[0][m * P + c0];
        d[0] = (_Float16)a.x; d[1] = (_Float16)a.y;
        d[2] = (_Float16)a.z; d[3] = (_Float16)a.w;
        d[4] = (_Float16)c.x; d[5] = (_Float16)c.y;
        d[6] = (_Float16)c.z; d[7] = (_Float16)c.w;
    }

    // ---- prefetch Z for t = 0 ----
    f32x4 zf0, zf1;
    {
        const float* zp = ZO + ((size_t)0 * NB + b0 + lg * 4) * NH;
        #pragma unroll
        for (int r = 0; r < 4; ++r) {
            zf0[r] = zp[r * NH + n0];
            zf1[r] = zp[r * NH + n1];
        }
    }
    __syncthreads();   // full barrier once, pre-loop

    int cur = 0;
    for (int t = 0; t < NT; ++t) {
        // A-fragments: h[m=ln][k = kt*16 + lg*4 ..+4), 16 x ds_read_b64
        half4v af[16];
        #pragma unroll
        for (int kt = 0; kt < 16; ++kt)
            af[kt] = *(const half4v*)&hl[cur][ln * P + kt * 16 + lg * 4];

        // acc = Z_t; then issue Z_{t+1} prefetch (stays in flight past BAR)
        f32x4 acc0 = zf0, acc1 = zf1;
        {
            const int tn = (t + 1 < NT) ? t + 1 : t;
            const float* zp = ZO + ((size_t)tn * NB + b0 + lg * 4) * NH;
            #pragma unroll
            for (int r = 0; r < 4; ++r) {
                zf0[r] = zp[r * NH + n0];
                zf1[r] = zp[r * NH + n1];
            }
        }

        #pragma unroll
        for (int kt = 0; kt < 16; ++kt) {
            acc0 = MFMA16(af[kt], wf0[kt], acc0);
            acc1 = MFMA16(af[kt], wf1[kt], acc1);
        }

        // sigmoid -> global f32 store + f16 LDS write (next buffer)
        {
            float* op = ZO + ((size_t)t * NB + b0 + lg * 4) * NH;
            _Float16* lp = &hl[cur ^ 1][(lg * 4) * P];
            #pragma unroll
            for (int r = 0; r < 4; ++r) {
                const float v0 = 1.0f / (1.0f + __expf(-acc0[r]));
                const float v1 = 1.0f / (1.0f + __expf(-acc1[r]));
                op[r * NH + n0] = v0;
                op[r * NH + n1] = v1;
                lp[r * P + n0] = (_Float16)v0;
                lp[r * P + n1] = (_Float16)v1;
            }
        }
        BAR();
        cur ^= 1;
    }
}

extern "C" void kernel_launch(void* const* d_in, const int* in_sizes, int n_in,
                              void* d_out, int out_size, void* d_ws, size_t ws_size,
                              hipStream_t stream) {
    const float* X  = (const float*)d_in[0];
    const float* h0 = (const float*)d_in[1];
    const float* Wi = (const float*)d_in[2];
    const float* Wh = (const float*)d_in[3];
    const float* bh = (const float*)d_in[4];
    float* out = (float*)d_out;

    dim3 zgrid((NT * NB) / 64, NH / 64);
    zprep_kernel<<<zgrid, 256, 0, stream>>>(X, Wi, bh, out);
    rnn_step_kernel<<<NB / 16, 512, 0, stream>>>(out, h0, Wh);
}